// Round 6
// baseline (3677.510 us; speedup 1.0000x reference)
//
#include <hip/hip_runtime.h>
#include <math.h>

#define N_NODES 30000
#define N_EDGES 480000
#define IN_F    512
#define HID     256
#define NEXP    64
#define CAP     2048
#define BN_EPS  1e-5f

static __device__ __forceinline__ float gelu_exact(float x) {
    return 0.5f * x * (1.0f + erff(x * 0.70710678118654752f));
}

// ---------------------------------------------------------------------------
// Graph preprocessing: degree count, dinv, CSR build (counting sort by dst)
// ---------------------------------------------------------------------------
__global__ void count_dst_k(const int* __restrict__ ei, int* __restrict__ cnt) {
    int e = blockIdx.x * 256 + threadIdx.x;   // grid exactly covers N_EDGES
    if (e < N_EDGES) atomicAdd(&cnt[ei[N_EDGES + e]], 1);
}

__global__ void dinv_k(const int* __restrict__ cnt, float* __restrict__ dinv) {
    int n = blockIdx.x * 256 + threadIdx.x;
    if (n < N_NODES) dinv[n] = rsqrtf((float)cnt[n] + 1.0f);   // +1 self loop
}

__global__ __launch_bounds__(1024) void scan_csr_k(const int* __restrict__ cnt, int* __restrict__ off) {
    __shared__ int part[1024];
    const int CH = 30;                         // 1024*30 = 30720 >= 30001
    int t = threadIdx.x;
    int base = t * CH;
    int s = 0;
    for (int i = 0; i < CH; ++i) { int g = base + i; if (g < N_NODES) s += cnt[g]; }
    part[t] = s;
    __syncthreads();
    for (int d = 1; d < 1024; d <<= 1) {
        int v = (t >= d) ? part[t - d] : 0;
        __syncthreads();
        part[t] += v;
        __syncthreads();
    }
    int run = part[t] - s;                     // exclusive prefix at chunk start
    for (int i = 0; i < CH; ++i) {
        int g = base + i;
        if (g <= N_NODES) off[g] = run;
        if (g < N_NODES) run += cnt[g];
    }
}

__global__ void scatter_edges_k(const int* __restrict__ ei, const float* __restrict__ dinv,
                                const int* __restrict__ off, int* __restrict__ cursor,
                                int* __restrict__ csr_src, float* __restrict__ csr_w) {
    int e = blockIdx.x * 256 + threadIdx.x;
    if (e >= N_EDGES) return;
    int s = ei[e];
    int d = ei[N_EDGES + e];
    int p = atomicAdd(&cursor[d], 1);
    int pos = off[d] + p;
    csr_src[pos] = s;
    csr_w[pos] = dinv[s] * dinv[d];
}

// ---------------------------------------------------------------------------
// Generic fp32 tiled GEMM: BM=BN=128, BK=8, 256 threads, 8x8 per-thread tile.
// VARIANT 0: C[M,N] = A[M,K]*B[K,N] (+bias if non-null)
// VARIANT 1: expert stage 1: A rows gathered via token list, gelu(.+b1) -> H1
// VARIANT 2: expert stage 2: A = H1 rows, (.+b2)*gate atomicAdd into core rows
// Experts are capped at CAP rows (reference drop semantics: stable rank >= CAP
// contributes nothing).
// ---------------------------------------------------------------------------
template <int VARIANT>
__global__ __launch_bounds__(256)
void gemm_k(const float* __restrict__ A, const float* __restrict__ B,
            float* __restrict__ C, const float* __restrict__ bias,
            int M, int N, int K, int lda, int ldb, int ldc,
            const int* __restrict__ ecnt, const int* __restrict__ eoff,
            const int* __restrict__ tok, const float* __restrict__ gate) {
    __shared__ float As[8][128];
    __shared__ float Bs[8][128];

    int tid = threadIdx.x;
    int n0 = blockIdx.x * 128;
    int m0 = blockIdx.y * 128;

    int Mb = M;
    const float* Bp = B;
    const float* bp = bias;
    const int*   tokE = nullptr;
    const float* gateE = nullptr;
    int eo = 0;
    if constexpr (VARIANT != 0) {
        int e = blockIdx.z;
        int cnt = ecnt[e];
        Mb = min(cnt, CAP);                  // reference capacity-drop semantics
        if (m0 >= Mb) return;
        eo = eoff[e];
        tokE = tok + eo;
        gateE = gate + eo;
        if constexpr (VARIANT == 1) {
            Bp = B + (size_t)e * 256 * 512;
            bp = bias + e * 512;
        } else {
            Bp = B + (size_t)e * 512 * 256;
            bp = bias + e * 256;
        }
    }

    int la_row = tid >> 1;            // 0..127
    int la_col = (tid & 1) * 4;       // 0 or 4
    int lb_row = tid >> 5;            // 0..7
    int lb_col = (tid & 31) * 4;      // 0..124
    int tx = tid & 15, ty = tid >> 4;

    float acc[8][8];
#pragma unroll
    for (int i = 0; i < 8; ++i)
#pragma unroll
        for (int j = 0; j < 8; ++j) acc[i][j] = 0.f;

    // A row pointer for the loader thread
    bool a_ok = (m0 + la_row) < Mb;
    const float* aptr;
    if constexpr (VARIANT == 1) {
        int r = a_ok ? tokE[m0 + la_row] : 0;
        aptr = A + (size_t)r * lda;
    } else if constexpr (VARIANT == 2) {
        int r = a_ok ? (eo + m0 + la_row) : eo;
        aptr = A + (size_t)r * lda;
    } else {
        int r = a_ok ? (m0 + la_row) : 0;
        aptr = A + (size_t)r * lda;
    }

    bool b_ok_col = (n0 + lb_col) < N;   // N is a multiple of 4 everywhere here

    int nk = K >> 3;
    for (int kt = 0; kt < nk; ++kt) {
        int k0 = kt << 3;
        float4 av = make_float4(0.f, 0.f, 0.f, 0.f);
        if (a_ok) av = *(const float4*)(aptr + k0 + la_col);
        As[la_col + 0][la_row] = av.x;
        As[la_col + 1][la_row] = av.y;
        As[la_col + 2][la_row] = av.z;
        As[la_col + 3][la_row] = av.w;

        float4 bv = make_float4(0.f, 0.f, 0.f, 0.f);
        if (b_ok_col) bv = *(const float4*)(Bp + (size_t)(k0 + lb_row) * ldb + n0 + lb_col);
        *(float4*)&Bs[lb_row][lb_col] = bv;

        __syncthreads();
#pragma unroll
        for (int k = 0; k < 8; ++k) {
            float a[8], b[8];
            *(float4*)&a[0] = *(const float4*)&As[k][ty * 8];
            *(float4*)&a[4] = *(const float4*)&As[k][ty * 8 + 4];
            *(float4*)&b[0] = *(const float4*)&Bs[k][tx * 8];
            *(float4*)&b[4] = *(const float4*)&Bs[k][tx * 8 + 4];
#pragma unroll
            for (int i = 0; i < 8; ++i)
#pragma unroll
                for (int j = 0; j < 8; ++j)
                    acc[i][j] = fmaf(a[i], b[j], acc[i][j]);
        }
        __syncthreads();
    }

    // epilogue
#pragma unroll
    for (int i = 0; i < 8; ++i) {
        int m = m0 + ty * 8 + i;
        if (m >= Mb) continue;
        if constexpr (VARIANT == 0) {
            float* crow = C + (size_t)m * ldc;
#pragma unroll
            for (int j = 0; j < 8; ++j) {
                int n = n0 + tx * 8 + j;
                if (n < N) {
                    float v = acc[i][j];
                    if (bias) v += bias[n];
                    crow[n] = v;
                }
            }
        } else if constexpr (VARIANT == 1) {
            float* crow = C + (size_t)(eo + m) * 512;
#pragma unroll
            for (int j = 0; j < 8; ++j) {
                int n = n0 + tx * 8 + j;
                crow[n] = gelu_exact(acc[i][j] + bp[n]);
            }
        } else {
            int t = tokE[m];
            float g = gateE[m];
            float* crow = C + (size_t)t * 256;
#pragma unroll
            for (int j = 0; j < 8; ++j) {
                int n = n0 + tx * 8 + j;
                atomicAdd(&crow[n], g * (acc[i][j] + bp[n]));
            }
        }
    }
}

// ---------------------------------------------------------------------------
// CSR gather aggregation + residual + bias + relu
// ---------------------------------------------------------------------------
__global__ __launch_bounds__(256)
void aggregate_k(const float* __restrict__ hc, const float* __restrict__ hr,
                 const float* __restrict__ bc, const float* __restrict__ br,
                 const int* __restrict__ off, const int* __restrict__ csr_src,
                 const float* __restrict__ csr_w, const float* __restrict__ dinv,
                 float* __restrict__ h) {
    int n = blockIdx.x;
    int f = threadIdx.x;
    int beg = off[n], end = off[n + 1];
    float di = dinv[n];
    float acc = di * di * hc[(size_t)n * 256 + f];   // self loop
    for (int j = beg; j < end; ++j) {
        int s = csr_src[j];
        float w = csr_w[j];
        acc = fmaf(w, hc[(size_t)s * 256 + f], acc);
    }
    float v = acc + bc[f] + hr[(size_t)n * 256 + f] + br[f];
    h[(size_t)n * 256 + f] = fmaxf(v, 0.f);
}

// ---------------------------------------------------------------------------
// Gating: logits = h@Wg + bg (64 experts = 64 lanes), fp64 accumulation,
// top-2 in fp64, softmax-of-2. One wave = 4 nodes; block = 16 nodes.
// ---------------------------------------------------------------------------
__global__ __launch_bounds__(256)
void gating_k(const float* __restrict__ h, const float* __restrict__ Wg,
              const float* __restrict__ bg, int* __restrict__ eidx,
              float* __restrict__ gval) {
    __shared__ float rows[16][256];
    int tid = threadIdx.x;
    int lane = tid & 63;
    int wave = tid >> 6;
    int nbase = blockIdx.x * 16 + wave * 4;

    for (int q = 0; q < 4; ++q) {
        const float* hr = h + (size_t)(nbase + q) * 256;
        for (int c = 0; c < 4; ++c)
            rows[wave * 4 + q][lane + 64 * c] = hr[lane + 64 * c];
    }
    // wave-private LDS rows; in-wave ordering handles the dependency

    double b = (double)bg[lane];
    double acc0 = b, acc1 = b, acc2 = b, acc3 = b;
    for (int k = 0; k < 256; ++k) {
        double w = (double)Wg[k * 64 + lane];
        acc0 = fma((double)rows[wave * 4 + 0][k], w, acc0);
        acc1 = fma((double)rows[wave * 4 + 1][k], w, acc1);
        acc2 = fma((double)rows[wave * 4 + 2][k], w, acc2);
        acc3 = fma((double)rows[wave * 4 + 3][k], w, acc3);
    }
    double accs[4] = {acc0, acc1, acc2, acc3};
    for (int q = 0; q < 4; ++q) {
        int n = nbase + q;
        // top-1 (ties -> smaller index, matching lax.top_k)
        double v = accs[q]; int idx = lane;
#pragma unroll
        for (int o = 32; o > 0; o >>= 1) {
            double ov = __shfl_xor(v, o);
            int oi = __shfl_xor(idx, o);
            if (ov > v || (ov == v && oi < idx)) { v = ov; idx = oi; }
        }
        double v0 = v; int e0 = idx;
        // top-2: exclude e0 by index
        v = (lane == e0) ? -1e300 : accs[q]; idx = lane;
#pragma unroll
        for (int o = 32; o > 0; o >>= 1) {
            double ov = __shfl_xor(v, o);
            int oi = __shfl_xor(idx, o);
            if (ov > v || (ov == v && oi < idx)) { v = ov; idx = oi; }
        }
        double v1 = v; int e1 = idx;
        if (lane == 0) {
            double ex = exp(v1 - v0);      // <= 1
            double inv = 1.0 / (1.0 + ex);
            eidx[2 * n] = e0; eidx[2 * n + 1] = e1;
            gval[2 * n] = (float)inv; gval[2 * n + 1] = (float)(ex * inv);
        }
    }
}

__global__ void ecount_k(const int* __restrict__ eidx, int* __restrict__ ecnt) {
    int t = blockIdx.x * 256 + threadIdx.x;
    if (t < 2 * N_NODES) atomicAdd(&ecnt[eidx[t]], 1);
}

__global__ void scan64_k(const int* __restrict__ ecnt, int* __restrict__ eoff) {
    int lane = threadIdx.x;
    int v = ecnt[lane];
    int s = v;
    for (int o = 1; o < 64; o <<= 1) {
        int t = __shfl_up(s, o);
        if (lane >= o) s += t;
    }
    eoff[lane] = s - v;   // exclusive
}

// ---------------------------------------------------------------------------
// STABLE dispatch: one block per expert; rank of token t within its expert is
// the count of earlier tokens (ascending flat index t = 2*node+slot) with the
// same expert — exactly jnp.argsort(stable) + searchsorted rank. Tokens with
// rank >= CAP are still written (slots exist) but GEMMs cap Mb at CAP, which
// reproduces the reference's drop semantics exactly and deterministically.
// ---------------------------------------------------------------------------
__global__ __launch_bounds__(256)
void dispatch_stable_k(const int* __restrict__ eidx, const float* __restrict__ gval,
                       const int* __restrict__ eoff,
                       int* __restrict__ tok, float* __restrict__ gsort) {
    __shared__ int part[256];
    int e = blockIdx.x;
    int tid = threadIdx.x;
    const int CH = (2 * N_NODES + 255) / 256;          // 235
    int t0 = tid * CH;
    int t1 = min(t0 + CH, 2 * N_NODES);
    int c = 0;
    for (int t = t0; t < t1; ++t) c += (eidx[t] == e);
    part[tid] = c;
    __syncthreads();
    for (int d = 1; d < 256; d <<= 1) {
        int v = (tid >= d) ? part[tid - d] : 0;
        __syncthreads();
        part[tid] += v;
        __syncthreads();
    }
    int pos = part[tid] - c;                           // exclusive prefix = stable rank base
    int base = eoff[e];
    for (int t = t0; t < t1; ++t) {
        if (eidx[t] == e) {
            tok[base + pos] = t >> 1;
            gsort[base + pos] = gval[t];
            ++pos;
        }
    }
}

// ---------------------------------------------------------------------------
// BatchNorm: TWO-PASS per-feature mean/var (biased) to avoid E[x^2]-mu^2
// catastrophic cancellation on low-variance ReLU'd features.
// ---------------------------------------------------------------------------
__global__ __launch_bounds__(256)
void bnstat1_k(const float* __restrict__ h, const float* __restrict__ core,
               float* __restrict__ z, float* __restrict__ bsum) {
    int f = threadIdx.x;
    int r0 = blockIdx.x * 235;
    int r1 = min(r0 + 235, N_NODES);
    float s = 0.f;
    for (int r = r0; r < r1; ++r) {
        size_t i = (size_t)r * 256 + f;
        float v = h[i] + core[i];
        z[i] = v;
        s += v;
    }
    atomicAdd(&bsum[f], s);
}

__global__ void bnmu_k(const float* __restrict__ bsum, float* __restrict__ mu) {
    int f = threadIdx.x;
    mu[f] = bsum[f] * (1.f / N_NODES);
}

__global__ __launch_bounds__(256)
void bnstat2_k(const float* __restrict__ z, const float* __restrict__ mu,
               float* __restrict__ bsq) {
    int f = threadIdx.x;
    float m = mu[f];
    int r0 = blockIdx.x * 235;
    int r1 = min(r0 + 235, N_NODES);
    float s2 = 0.f;
    for (int r = r0; r < r1; ++r) {
        float d = z[(size_t)r * 256 + f] - m;
        s2 = fmaf(d, d, s2);
    }
    atomicAdd(&bsq[f], s2);
}

__global__ void bnfinal_k(const float* __restrict__ bsq, const float* __restrict__ mu,
                          const float* __restrict__ gamma, const float* __restrict__ beta,
                          float* __restrict__ scale, float* __restrict__ shift) {
    int f = threadIdx.x;
    float var = bsq[f] * (1.f / N_NODES);
    float rstd = rsqrtf(var + BN_EPS);
    float sc = gamma[f] * rstd;
    scale[f] = sc;
    shift[f] = beta[f] - mu[f] * sc;
}

__global__ __launch_bounds__(256)
void bnapply_k(const float* __restrict__ z, const float* __restrict__ scale,
               const float* __restrict__ shift, float* __restrict__ out) {
    int i = blockIdx.x * 256 + threadIdx.x;
    int stride = gridDim.x * 256;
    const int total4 = N_NODES * 256 / 4;
    for (; i < total4; i += stride) {
        float4 v = ((const float4*)z)[i];
        int f = (i * 4) & 255;
        float4 sc = *(const float4*)&scale[f];
        float4 sh = *(const float4*)&shift[f];
        float4 r;
        r.x = fmaf(v.x, sc.x, sh.x);
        r.y = fmaf(v.y, sc.y, sh.y);
        r.z = fmaf(v.z, sc.z, sh.z);
        r.w = fmaf(v.w, sc.w, sh.w);
        ((float4*)out)[i] = r;
    }
}

// ---------------------------------------------------------------------------
extern "C" void kernel_launch(void* const* d_in, const int* in_sizes, int n_in,
                              void* d_out, int out_size, void* d_ws, size_t ws_size,
                              hipStream_t stream) {
    const float* x  = (const float*)d_in[0];
    const int*   ei = (const int*)d_in[1];
    const float* Wc[2]    = {(const float*)d_in[2],  (const float*)d_in[14]};
    const float* bc[2]    = {(const float*)d_in[3],  (const float*)d_in[15]};
    const float* Wr[2]    = {(const float*)d_in[4],  (const float*)d_in[16]};
    const float* br[2]    = {(const float*)d_in[5],  (const float*)d_in[17]};
    const float* Wg[2]    = {(const float*)d_in[6],  (const float*)d_in[18]};
    const float* bg[2]    = {(const float*)d_in[7],  (const float*)d_in[19]};
    const float* W1[2]    = {(const float*)d_in[8],  (const float*)d_in[20]};
    const float* b1[2]    = {(const float*)d_in[9],  (const float*)d_in[21]};
    const float* W2[2]    = {(const float*)d_in[10], (const float*)d_in[22]};
    const float* b2[2]    = {(const float*)d_in[11], (const float*)d_in[23]};
    const float* gamma[2] = {(const float*)d_in[12], (const float*)d_in[24]};
    const float* beta[2]  = {(const float*)d_in[13], (const float*)d_in[25]};
    const float* Wf = (const float*)d_in[26];
    const float* bf = (const float*)d_in[27];

    char* w = (char*)d_ws;
    auto alloc = [&](size_t bytes) {
        char* p = w;
        w += (bytes + 255) & ~(size_t)255;
        return p;
    };
    int*   cnt     = (int*)alloc(N_NODES * 4);
    int*   cursor  = (int*)alloc(N_NODES * 4);
    float* dinv    = (float*)alloc(N_NODES * 4);
    int*   csr_off = (int*)alloc((N_NODES + 1) * 4);
    int*   csr_src = (int*)alloc(N_EDGES * 4);
    float* csr_w   = (float*)alloc(N_EDGES * 4);
    float* bufA    = (float*)alloc((size_t)N_NODES * 256 * 4);  // hc / x2
    float* bufB    = (float*)alloc((size_t)N_NODES * 256 * 4);  // hr / z
    float* hbuf    = (float*)alloc((size_t)N_NODES * 256 * 4);  // GCN output h
    float* core    = (float*)alloc((size_t)N_NODES * 256 * 4);  // MoE output
    float* H1      = (float*)alloc((size_t)2 * N_NODES * 512 * 4);  // 122.9 MB
    float* x1      = H1;  // alias: x1 (layer-0 BN out) dead before layer-1 E1 writes H1
    int*   eidx    = (int*)alloc(2 * N_NODES * 4);
    float* gval    = (float*)alloc(2 * N_NODES * 4);
    int*   ecnt    = (int*)alloc(256);
    int*   eoff    = (int*)alloc(256);
    int*   tok     = (int*)alloc(2 * N_NODES * 4);
    float* gsort   = (float*)alloc(2 * N_NODES * 4);
    float* bnsum   = (float*)alloc(1024);
    float* bnsq    = (float*)alloc(1024);
    float* bnmu    = (float*)alloc(1024);
    float* bnscale = (float*)alloc(1024);
    float* bnshift = (float*)alloc(1024);

    // ---- graph structure (once) ----
    hipMemsetAsync(cnt, 0, N_NODES * 4, stream);
    count_dst_k<<<N_EDGES / 256, 256, 0, stream>>>(ei, cnt);
    dinv_k<<<(N_NODES + 255) / 256, 256, 0, stream>>>(cnt, dinv);
    scan_csr_k<<<1, 1024, 0, stream>>>(cnt, csr_off);
    hipMemsetAsync(cursor, 0, N_NODES * 4, stream);
    scatter_edges_k<<<N_EDGES / 256, 256, 0, stream>>>(ei, dinv, csr_off, cursor, csr_src, csr_w);

    const float* xin = x;
    int Kl = IN_F;
    for (int l = 0; l < 2; ++l) {
        dim3 gdense(2, (N_NODES + 127) / 128);
        // hc = xin @ Wc ; hr = xin @ Wr  (biases folded into aggregate)
        gemm_k<0><<<gdense, 256, 0, stream>>>(xin, Wc[l], bufA, nullptr,
            N_NODES, 256, Kl, Kl, 256, 256, nullptr, nullptr, nullptr, nullptr);
        gemm_k<0><<<gdense, 256, 0, stream>>>(xin, Wr[l], bufB, nullptr,
            N_NODES, 256, Kl, Kl, 256, 256, nullptr, nullptr, nullptr, nullptr);
        aggregate_k<<<N_NODES, 256, 0, stream>>>(bufA, bufB, bc[l], br[l],
            csr_off, csr_src, csr_w, dinv, hbuf);

        gating_k<<<N_NODES / 16, 256, 0, stream>>>(hbuf, Wg[l], bg[l], eidx, gval);
        hipMemsetAsync(ecnt, 0, 64 * 4, stream);
        ecount_k<<<(2 * N_NODES + 255) / 256, 256, 0, stream>>>(eidx, ecnt);
        scan64_k<<<1, 64, 0, stream>>>(ecnt, eoff);
        dispatch_stable_k<<<NEXP, 256, 0, stream>>>(eidx, gval, eoff, tok, gsort);

        // expert FFN: H1 = gelu(gather(h)@W1 + b1) ; core += gate*(H1@W2 + b2)
        gemm_k<1><<<dim3(4, 16, 64), 256, 0, stream>>>(hbuf, W1[l], H1, b1[l],
            0, 512, 256, 256, 512, 512, ecnt, eoff, tok, gsort);
        hipMemsetAsync(core, 0, (size_t)N_NODES * 256 * 4, stream);
        gemm_k<2><<<dim3(2, 16, 64), 256, 0, stream>>>(H1, W2[l], core, b2[l],
            0, 256, 512, 512, 256, 256, ecnt, eoff, tok, gsort);

        // BN(h + core), two-pass
        hipMemsetAsync(bnsum, 0, 1024, stream);
        hipMemsetAsync(bnsq, 0, 1024, stream);
        bnstat1_k<<<128, 256, 0, stream>>>(hbuf, core, bufB, bnsum);
        bnmu_k<<<1, 256, 0, stream>>>(bnsum, bnmu);
        bnstat2_k<<<128, 256, 0, stream>>>(bufB, bnmu, bnsq);
        bnfinal_k<<<1, 256, 0, stream>>>(bnsq, bnmu, gamma[l], beta[l], bnscale, bnshift);
        float* xout = (l == 0) ? x1 : bufA;
        bnapply_k<<<2048, 256, 0, stream>>>(bufB, bnscale, bnshift, xout);
        xin = xout;
        Kl = HID;
    }

    // final projection: out = x2 @ Wf + bf   (N=40)
    gemm_k<0><<<dim3(1, (N_NODES + 127) / 128), 256, 0, stream>>>(xin, Wf, (float*)d_out, bf,
        N_NODES, 40, 256, 256, 40, 40, nullptr, nullptr, nullptr, nullptr);
    (void)in_sizes; (void)n_in; (void)out_size; (void)ws_size;
}